// Round 10
// baseline (56.156 us; speedup 1.0000x reference)
//
#include <hip/hip_runtime.h>
#include <math.h>

#define NB   16
#define NQ   4096
#define NTGT 128
#define CELEMS (NB * NQ * NTGT)

#define NSLOT 64           // rowkey slots per batch (= cost blocks per batch)
#define AT   256           // augment threads
#define ACPT (NQ / AT)     // 16 cols per thread in augment
#define ANW  (AT / 64)     // 4 waves

typedef unsigned long long u64;

// ---------------- kernel 1: cost matrix + per-row (target) min/argmin --------
// Grid 1024 x 256. Block covers 64 q x 128 t (each thread 8 q x 4 t cells).
// float4 loads/stores coalesced. Per-row key (cost_bits<<32 | q; u64-min ==
// min cost then lowest q) reduced in LDS, plain-stored to rowkey2[b][blk][t].
__global__ __launch_bounds__(256) void cost_kernel(
    const float* __restrict__ outputs,
    const float* __restrict__ targets,
    float* __restrict__ C,
    u64*   __restrict__ rowkey2)      // [NB][NSLOT][NTGT]
{
    __shared__ u64 part[8][NTGT];     // 8 KB
    const int tid  = threadIdx.x;
    const int t4   = tid & 31;
    const int qloc = tid >> 5;
    const int b    = blockIdx.x >> 6;            // 64 blocks per batch
    const int blk  = blockIdx.x & (NSLOT - 1);
    const int idx0 = blockIdx.x * 2048 + tid;

    const float4* tg = reinterpret_cast<const float4*>(targets) + (b << 7) + (t4 << 2);
    float4 g[4];
    #pragma unroll
    for (int f = 0; f < 4; ++f) g[f] = tg[f];

    u64 keymin[4] = {~0ull, ~0ull, ~0ull, ~0ull};

    #pragma unroll
    for (int e = 0; e < 8; ++e) {
        int idx = idx0 + 256 * e;
        int bq  = idx >> 5;
        float4 o = reinterpret_cast<const float4*>(outputs)[bq];
        u64 q = (u64)(unsigned)(bq & (NQ - 1));
        float r[4];
        #pragma unroll
        for (int f = 0; f < 4; ++f) {
            float4 gg = g[f];
            r[f] = (fabsf(o.x - gg.x) + fabsf(o.y - gg.y)) +
                   (fabsf(o.z - gg.z) + fabsf(o.w - gg.w));
            u64 key = (((u64)__float_as_uint(r[f])) << 32) | q;
            if (key < keymin[f]) keymin[f] = key;
        }
        reinterpret_cast<float4*>(C)[idx] = make_float4(r[0], r[1], r[2], r[3]);
    }

    #pragma unroll
    for (int f = 0; f < 4; ++f) part[qloc][(t4 << 2) + f] = keymin[f];
    __syncthreads();

    if (tid < NTGT) {
        u64 k = part[0][tid];
        #pragma unroll
        for (int qq = 1; qq < 8; ++qq) { u64 ov = part[qq][tid]; if (ov < k) k = ov; }
        rowkey2[(((size_t)b * NSLOT) + blk) * NTGT + tid] = k;
    }
}

// ---------------- kernel 2: rowkey reduce + greedy tight-edge claim ----------
// One block (512 thr) per batch. u[i]=rowmin[i], v=0 (dual feasible);
// row i claims its argmin column (tight edge), lowest row wins. State to ws.
__global__ __launch_bounds__(512) void claim_kernel(
    const u64* __restrict__ rowkey2,
    double* __restrict__ u_ws,        // [NB][NTGT]
    short*  __restrict__ row4col_ws,  // [NB][NQ]
    short*  __restrict__ col4row_ws,  // [NB][NTGT]
    short*  __restrict__ left_ws,     // [NB][NTGT]
    int*    __restrict__ nleft_ws)    // [NB]
{
    __shared__ u64      red2_[4][NTGT];   // 4 KB
    __shared__ unsigned claim_[NQ];       // 16 KB
    __shared__ int      rowarg_[NTGT];
    __shared__ u64      bmask[2];

    const int tid = threadIdx.x;
    const int b   = blockIdx.x;

    #pragma unroll
    for (int kk = 0; kk < NQ / 512; ++kk) {
        int k = tid + 512 * kk;
        claim_[k] = 0xFFFFFFFFu;
        row4col_ws[b * NQ + k] = -1;
    }

    // reduce the 64 slot keys per row (coalesced)
    {
        const int t = tid & 127, s = tid >> 7;            // 4 slices x 16 slots
        const u64* rk = rowkey2 + (size_t)b * NSLOT * NTGT;
        u64 k = ~0ull;
        #pragma unroll
        for (int gg = 0; gg < NSLOT / 4; ++gg) {
            u64 ov = rk[(s * (NSLOT / 4) + gg) * NTGT + t];
            if (ov < k) k = ov;
        }
        red2_[s][t] = k;
    }
    __syncthreads();

    if (tid < NTGT) {
        u64 key = red2_[0][tid];
        #pragma unroll
        for (int s = 1; s < 4; ++s) { u64 ov = red2_[s][tid]; if (ov < key) key = ov; }
        u_ws[b * NTGT + tid] = (double)__uint_as_float((unsigned)(key >> 32));
        rowarg_[tid] = (int)(key & 0xffffffffu);
    }
    __syncthreads();

    if (tid < NTGT) atomicMin(&claim_[rowarg_[tid]], (unsigned)tid);
    __syncthreads();

    bool un = false;
    if (tid < NTGT) {
        int j = rowarg_[tid];
        bool won = (claim_[j] == (unsigned)tid);
        col4row_ws[b * NTGT + tid] = won ? (short)j : (short)-1;
        if (won) row4col_ws[b * NQ + j] = (short)tid;   // winners have distinct j
        un = !won;
    }
    {
        u64 m = __ballot(un);
        if ((tid & 63) == 0 && (tid >> 6) < 2) bmask[tid >> 6] = m;
    }
    __syncthreads();
    if (un) {
        int lane = tid & 63, w = tid >> 6;
        int r = __popcll(bmask[w] & ((1ull << lane) - 1)) + (w ? __popcll(bmask[0]) : 0);
        left_ws[b * NTGT + r] = (short)tid;
    }
    if (tid == 0) nleft_ws[b] = __popcll(bmask[0]) + __popcll(bmask[1]);
}

// ---------------- kernel 3: exact augmentation for leftover rows + output ----
// One block (256 thr) per batch. Scipy-equivalent f64 shortest-augmenting-path
// from the claim's duals -> provably optimal matching. Branchless scan,
// ONE barrier per Dijkstra iteration (parity-buffered reduce slots).
__global__ __launch_bounds__(AT) void augment_kernel(
    const float* __restrict__ outputs,
    const float* __restrict__ targets,
    const double* __restrict__ u_ws,
    const short*  __restrict__ row4col_ws,
    const short*  __restrict__ col4row_ws,
    const short*  __restrict__ left_ws,
    const int*    __restrict__ nleft_ws,
    float* __restrict__ row_out,   // [NB, NTGT] as float
    float* __restrict__ col_out)   // [NB, NTGT] as float
{
    __shared__ double v_[NQ];               // 32 KB
    __shared__ double shortest_[NQ];        // 32 KB
    __shared__ short  row4col_[NQ];         // 8 KB
    __shared__ unsigned char path_[NQ];     // 4 KB
    __shared__ float4 tgt_[NTGT];           // 2 KB
    __shared__ double u_[NTGT];             // 1 KB
    __shared__ short  col4row_[NTGT];
    __shared__ short  left_[NTGT];
    __shared__ int    sc_j[NTGT];
    __shared__ double red_val[2][ANW];
    __shared__ int    red_idx[2][ANW];

    const int tid = threadIdx.x;
    const int b   = blockIdx.x;
    const float4* outq = reinterpret_cast<const float4*>(outputs) + b * NQ;

    #pragma unroll
    for (int kk = 0; kk < ACPT; ++kk) {
        int k = tid + AT * kk;
        v_[k] = 0.0;
        row4col_[k] = row4col_ws[b * NQ + k];
    }
    if (tid < NTGT) {
        u_[tid]      = u_ws[b * NTGT + tid];
        col4row_[tid] = col4row_ws[b * NTGT + tid];
        left_[tid]   = left_ws[b * NTGT + tid];
        tgt_[tid]    = reinterpret_cast<const float4*>(targets)[b * NTGT + tid];
    }
    const int nleft = nleft_ws[b];
    __syncthreads();

    int parity = 0;

    for (int li = 0; li < nleft; ++li) {
        const int cur = left_[li];
        #pragma unroll
        for (int kk = 0; kk < ACPT; ++kk) shortest_[tid + AT * kk] = (double)INFINITY;
        unsigned rem  = 0xFFFFu;
        int    i      = cur;
        double minv   = 0.0;
        int    fj     = -1;
        int    Lns    = 0;

        while (true) {
            const double ui = u_[i];
            const float4 g  = tgt_[i];

            double bv = (double)INFINITY;
            int    bi = 0x7fffffff;

            // branchless scan: unconditional loads, masked compare/update
            #pragma unroll
            for (int kk = 0; kk < ACPT; ++kk) {
                int k = tid + AT * kk;
                float4 oo = outq[k];
                float  c  = (fabsf(oo.x - g.x) + fabsf(oo.y - g.y)) +
                            (fabsf(oo.z - g.z) + fabsf(oo.w - g.w));
                double cand = ((minv + (double)c) - ui) - v_[k];
                double sold = shortest_[k];
                bool valid  = (rem >> kk) & 1u;
                bool upd    = valid && (cand < sold);
                if (upd) { shortest_[k] = cand; path_[k] = (unsigned char)i; }
                double s = upd ? cand : sold;
                if (valid && s < bv) { bv = s; bi = k; }
            }

            // wave reduce with explicit (value, lowest-index) tie-break
            for (int off = 32; off > 0; off >>= 1) {
                double ov = __shfl_down(bv, off);
                int    oi = __shfl_down(bi, off);
                if (ov < bv || (ov == bv && oi < bi)) { bv = ov; bi = oi; }
            }
            if ((tid & 63) == 0) { red_val[parity][tid >> 6] = bv; red_idx[parity][tid >> 6] = bi; }
            __syncthreads();

            double fv = red_val[parity][0];
            int    jj = red_idx[parity][0];
            #pragma unroll
            for (int w = 1; w < ANW; ++w) {
                double ov = red_val[parity][w];
                int    oi = red_idx[parity][w];
                if (ov < fv || (ov == fv && oi < jj)) { fv = ov; jj = oi; }
            }
            parity ^= 1;           // next iteration uses the other slots

            fj   = jj;
            minv = fv;

            if ((fj & (AT - 1)) == tid) rem &= ~(1u << (fj >> 8));   // owner drops it

            int r = row4col_[fj];
            if (r < 0) break;                 // sink found
            if (tid == 0) sc_j[Lns] = fj;
            Lns++;
            i = r;
        }

        // ---- row end: duals + augment (tid0; reference op order) ----
        const double dfin = minv;
        if (tid == 0) {
            u_[cur] += dfin;
            for (int e = 0; e < Lns; ++e) {
                int j = sc_j[e];
                double d = dfin - shortest_[j];
                u_[row4col_[j]] += d;     // row reached via j; its matched col is j
                v_[j] -= d;               // sink term exactly 0, skipped
            }
            int j = fj;
            while (true) {
                int i2 = path_[j];
                row4col_[j] = (short)i2;
                int nj = col4row_[i2];
                col4row_[i2] = (short)j;
                j = nj;
                if (i2 == cur) break;
            }
        }
        __syncthreads();   // publish tid0's updates before next row's scan
    }

    // outputs (transposed case): order = argsort(col4row);
    // row_ind = col4row[order]; col_ind = order. Distinct values -> rank =
    // count of smaller values.
    if (tid < NTGT) {
        int val = col4row_[tid];
        int rank = 0;
        #pragma unroll
        for (int k = 0; k < NTGT; ++k) rank += (col4row_[k] < val);
        row_out[b * NTGT + rank] = (float)val;
        col_out[b * NTGT + rank] = (float)tid;
    }
}

extern "C" void kernel_launch(void* const* d_in, const int* in_sizes, int n_in,
                              void* d_out, int out_size, void* d_ws, size_t ws_size,
                              hipStream_t stream) {
    const float* outputs = (const float*)d_in[0];   // [16, 4096, 4]
    const float* targets = (const float*)d_in[1];   // [16, 128, 4]
    float* out = (float*)d_out;                     // C | row_ind | col_ind (as f32)

    char* ws = (char*)d_ws;
    u64*    rowkey2    = (u64*)ws;                                   // 1 MB
    double* u_ws       = (double*)(ws + (1 << 20));                  // 16 KB
    short*  row4col_ws = (short*)(ws + (1 << 20) + NB * NTGT * 8);   // 128 KB
    short*  col4row_ws = row4col_ws + NB * NQ;                       // 4 KB
    short*  left_ws    = col4row_ws + NB * NTGT;                     // 4 KB
    int*    nleft_ws   = (int*)(left_ws + NB * NTGT);                // 64 B

    hipLaunchKernelGGL(cost_kernel, dim3(NB * NSLOT), dim3(256), 0, stream,
                       outputs, targets, out, rowkey2);
    hipLaunchKernelGGL(claim_kernel, dim3(NB), dim3(512), 0, stream,
                       rowkey2, u_ws, row4col_ws, col4row_ws, left_ws, nleft_ws);
    hipLaunchKernelGGL(augment_kernel, dim3(NB), dim3(AT), 0, stream,
                       outputs, targets, u_ws, row4col_ws, col4row_ws, left_ws, nleft_ws,
                       out + CELEMS, out + CELEMS + NB * NTGT);
}

// Round 11
// 40.279 us; speedup vs baseline: 1.3942x; 1.3942x over previous
//
#include <hip/hip_runtime.h>
#include <math.h>

#define NB   16
#define NQ   4096
#define NTGT 128
#define CELEMS (NB * NQ * NTGT)

#define NSLOT 64           // rowkey slots per batch (= cost blocks per batch)
#define AT   256           // lsa threads
#define ACPT (NQ / AT)     // 16 cols per thread
#define ANW  (AT / 64)     // 4 waves

typedef unsigned long long u64;

// ---------------- kernel 1: cost matrix + per-row (target) min/argmin --------
// Grid 1024 x 256. Block covers 64 q x 128 t (each thread 8 q x 4 t cells).
// float4 loads/stores coalesced. Per-row key (cost_bits<<32 | q; u64-min ==
// min cost then lowest q) reduced in LDS, plain-stored to rowkey2[b][blk][t].
__global__ __launch_bounds__(256) void cost_kernel(
    const float* __restrict__ outputs,
    const float* __restrict__ targets,
    float* __restrict__ C,
    u64*   __restrict__ rowkey2)      // [NB][NSLOT][NTGT]
{
    __shared__ u64 part[8][NTGT];     // 8 KB
    const int tid  = threadIdx.x;
    const int t4   = tid & 31;
    const int qloc = tid >> 5;
    const int b    = blockIdx.x >> 6;            // 64 blocks per batch
    const int blk  = blockIdx.x & (NSLOT - 1);
    const int idx0 = blockIdx.x * 2048 + tid;

    const float4* tg = reinterpret_cast<const float4*>(targets) + (b << 7) + (t4 << 2);
    float4 g[4];
    #pragma unroll
    for (int f = 0; f < 4; ++f) g[f] = tg[f];

    u64 keymin[4] = {~0ull, ~0ull, ~0ull, ~0ull};

    #pragma unroll
    for (int e = 0; e < 8; ++e) {
        int idx = idx0 + 256 * e;
        int bq  = idx >> 5;
        float4 o = reinterpret_cast<const float4*>(outputs)[bq];
        u64 q = (u64)(unsigned)(bq & (NQ - 1));
        float r[4];
        #pragma unroll
        for (int f = 0; f < 4; ++f) {
            float4 gg = g[f];
            r[f] = (fabsf(o.x - gg.x) + fabsf(o.y - gg.y)) +
                   (fabsf(o.z - gg.z) + fabsf(o.w - gg.w));
            u64 key = (((u64)__float_as_uint(r[f])) << 32) | q;
            if (key < keymin[f]) keymin[f] = key;
        }
        reinterpret_cast<float4*>(C)[idx] = make_float4(r[0], r[1], r[2], r[3]);
    }

    #pragma unroll
    for (int f = 0; f < 4; ++f) part[qloc][(t4 << 2) + f] = keymin[f];
    __syncthreads();

    if (tid < NTGT) {
        u64 k = part[0][tid];
        #pragma unroll
        for (int qq = 1; qq < 8; ++qq) { u64 ov = part[qq][tid]; if (ov < k) k = ov; }
        rowkey2[(((size_t)b * NSLOT) + blk) * NTGT + tid] = k;
    }
}

// ---------------- kernel 2: fused claim + exact augmentation + output --------
// One block (256 thr) per batch; transposed problem (128 rows x 4096 cols).
// u[i]=rowmin[i], v=0 (dual feasible); greedy tight-edge claim; leftover rows
// run exact f64 shortest-augmenting-path from these duals (provably optimal
// matching; unique optimum for random floats -> identical indices to scipy).
// Iteration-1 of each Dijkstra is resolved analytically (it always picks the
// contested argmin j0 with minv=0), and reference-iterations 1+2 are fused
// into a single two-row scan -> one reduce+barrier saved per leftover row.
__global__ __launch_bounds__(AT, 1) void lsa_kernel(
    const float* __restrict__ outputs,
    const float* __restrict__ targets,
    const u64*   __restrict__ rowkey2,
    float* __restrict__ row_out,   // [NB, NTGT] as float
    float* __restrict__ col_out)   // [NB, NTGT] as float
{
    __shared__ float4 out_lds[NQ];          // 64 KB
    __shared__ double v_[NQ];               // 32 KB
    __shared__ double shortest_[NQ];        // 32 KB (aliased as u32 claim_[] pre-Dijkstra)
    __shared__ short  row4col_[NQ];         // 8 KB
    __shared__ unsigned char path_[NQ];     // 4 KB
    __shared__ float4 tgt_[NTGT];           // 2 KB
    __shared__ double u_[NTGT];             // 1 KB
    __shared__ u64    red2_[2][NTGT];       // 2 KB
    __shared__ int    rowarg_[NTGT];
    __shared__ short  col4row_[NTGT];
    __shared__ short  left_[NTGT];
    __shared__ int    sc_j[NTGT];
    __shared__ double red_val[2][ANW];
    __shared__ int    red_idx[2][ANW];
    __shared__ u64    bmask_[2];

    const int tid = threadIdx.x;
    const int b   = blockIdx.x;
    const float4* outq = reinterpret_cast<const float4*>(outputs) + b * NQ;
    unsigned* claim_ = (unsigned*)shortest_;   // dead storage during claim phase

    // prologue: stage outputs, init column state
    #pragma unroll
    for (int kk = 0; kk < ACPT; ++kk) {
        int k = tid + AT * kk;
        out_lds[k] = outq[k];
        v_[k] = 0.0;
        row4col_[k] = -1;
        claim_[k] = 0xFFFFFFFFu;
    }

    // reduce the 64 rowkey slots per row (coalesced)
    {
        const int t = tid & 127, s = tid >> 7;            // 2 slices x 32 slots
        const u64* rk = rowkey2 + (size_t)b * NSLOT * NTGT;
        u64 k = ~0ull;
        #pragma unroll
        for (int gg = 0; gg < NSLOT / 2; ++gg) {
            u64 ov = rk[(s * (NSLOT / 2) + gg) * NTGT + t];
            if (ov < k) k = ov;
        }
        red2_[s][t] = k;
    }
    __syncthreads();

    if (tid < NTGT) {
        u64 key = red2_[0][tid];
        u64 ov  = red2_[1][tid]; if (ov < key) key = ov;
        u_[tid] = (double)__uint_as_float((unsigned)(key >> 32));
        rowarg_[tid] = (int)(key & 0xffffffffu);
        tgt_[tid] = reinterpret_cast<const float4*>(targets)[b * NTGT + tid];
    }
    __syncthreads();

    // greedy claim of tight edges: lowest row wins each contested column
    if (tid < NTGT) atomicMin(&claim_[rowarg_[tid]], (unsigned)tid);
    __syncthreads();

    bool un = false;
    if (tid < NTGT) {
        int j = rowarg_[tid];
        bool won = (claim_[j] == (unsigned)tid);
        col4row_[tid] = won ? (short)j : (short)-1;
        if (won) row4col_[j] = (short)tid;   // winners have distinct j
        un = !won;
    }
    {
        u64 m = __ballot(un);
        if ((tid & 63) == 0 && (tid >> 6) < 2) bmask_[tid >> 6] = m;
    }
    __syncthreads();
    const int nleft = __popcll(bmask_[0]) + __popcll(bmask_[1]);
    if (un) {
        int lane = tid & 63, w = tid >> 6;
        int r = __popcll(bmask_[w] & ((1ull << lane) - 1)) + (w ? __popcll(bmask_[0]) : 0);
        left_[r] = (short)tid;
    }
    __syncthreads();
    // claim_ alias of shortest_ now dead; shortest_ is set-on-first-scan per row

    int parity = 0;

    for (int li = 0; li < nleft; ++li) {
        const int cur = left_[li];
        const int j0  = rowarg_[cur];       // contested argmin: iteration-1's pick
        int    i      = row4col_[j0];       // winner row (always matched)
        double minv   = 0.0;
        int    fj     = j0;
        int    Lns    = 1;
        unsigned rem  = 0xFFFFu;
        if ((j0 & (AT - 1)) == tid) {
            rem &= ~(1u << (j0 >> 8));
            shortest_[j0] = 0.0;            // exact iteration-1 value
            path_[j0] = (unsigned char)cur;
        }
        if (tid == 0) sc_j[0] = j0;
        bool first = true;

        while (true) {
            const double ui = u_[i];
            const float4 g  = tgt_[i];

            double bv = (double)INFINITY;
            int    bi = 0x7fffffff;

            if (first) {
                // fused reference-iterations 1+2: shortest = min(cand_cur, cand_win),
                // path = winner only on strict < (matches reference update rule)
                const double uc = u_[cur];
                const float4 gc = tgt_[cur];
                #pragma unroll
                for (int kk = 0; kk < ACPT; ++kk) {
                    int k = tid + AT * kk;
                    float4 oo = out_lds[k];
                    float  cc = (fabsf(oo.x - gc.x) + fabsf(oo.y - gc.y)) +
                                (fabsf(oo.z - gc.z) + fabsf(oo.w - gc.w));
                    float  cw = (fabsf(oo.x - g.x) + fabsf(oo.y - g.y)) +
                                (fabsf(oo.z - g.z) + fabsf(oo.w - g.w));
                    double vk = v_[k];
                    double cand_c = ((0.0 + (double)cc) - uc) - vk;
                    double cand_w = ((0.0 + (double)cw) - ui) - vk;
                    bool wless = cand_w < cand_c;
                    double s = wless ? cand_w : cand_c;
                    if ((rem >> kk) & 1u) {
                        shortest_[k] = s;
                        path_[k] = (unsigned char)(wless ? i : cur);
                        if (s < bv) { bv = s; bi = k; }
                    }
                }
            } else {
                #pragma unroll
                for (int kk = 0; kk < ACPT; ++kk) {
                    int k = tid + AT * kk;
                    float4 oo = out_lds[k];
                    float  c  = (fabsf(oo.x - g.x) + fabsf(oo.y - g.y)) +
                                (fabsf(oo.z - g.z) + fabsf(oo.w - g.w));
                    double cand = ((minv + (double)c) - ui) - v_[k];
                    double sold = shortest_[k];
                    bool valid  = (rem >> kk) & 1u;
                    bool upd    = valid && (cand < sold);
                    if (upd) { shortest_[k] = cand; path_[k] = (unsigned char)i; }
                    double s = upd ? cand : sold;
                    if (valid && s < bv) { bv = s; bi = k; }
                }
            }
            first = false;

            // wave reduce with explicit (value, lowest-index) tie-break
            for (int off = 32; off > 0; off >>= 1) {
                double ov = __shfl_down(bv, off);
                int    oi = __shfl_down(bi, off);
                if (ov < bv || (ov == bv && oi < bi)) { bv = ov; bi = oi; }
            }
            if ((tid & 63) == 0) { red_val[parity][tid >> 6] = bv; red_idx[parity][tid >> 6] = bi; }
            __syncthreads();

            double fv = red_val[parity][0];
            int    jj = red_idx[parity][0];
            #pragma unroll
            for (int w = 1; w < ANW; ++w) {
                double ov = red_val[parity][w];
                int    oi = red_idx[parity][w];
                if (ov < fv || (ov == fv && oi < jj)) { fv = ov; jj = oi; }
            }
            parity ^= 1;           // next iteration uses the other slots

            fj   = jj;
            minv = fv;

            if ((fj & (AT - 1)) == tid) rem &= ~(1u << (fj >> 8));   // owner drops it

            int r = row4col_[fj];
            if (r < 0) break;                 // sink found
            if (tid == 0) sc_j[Lns] = fj;
            Lns++;
            i = r;
        }

        // ---- row end: duals + augment (tid0; reference op order) ----
        const double dfin = minv;
        if (tid == 0) {
            u_[cur] += dfin;
            for (int e = 0; e < Lns; ++e) {
                int j = sc_j[e];
                double d = dfin - shortest_[j];
                u_[row4col_[j]] += d;     // pre-augment matched row of j
                v_[j] -= d;               // sink term exactly 0, skipped
            }
            int j = fj;
            while (true) {
                int i2 = path_[j];
                row4col_[j] = (short)i2;
                int nj = col4row_[i2];
                col4row_[i2] = (short)j;
                j = nj;
                if (i2 == cur) break;
            }
        }
        __syncthreads();   // publish tid0's updates before next row's scan
    }

    // outputs (transposed case): order = argsort(col4row);
    // row_ind = col4row[order]; col_ind = order. Distinct values -> rank =
    // count of smaller values.
    if (tid < NTGT) {
        int val = col4row_[tid];
        int rank = 0;
        #pragma unroll
        for (int k = 0; k < NTGT; ++k) rank += (col4row_[k] < val);
        row_out[b * NTGT + rank] = (float)val;
        col_out[b * NTGT + rank] = (float)tid;
    }
}

extern "C" void kernel_launch(void* const* d_in, const int* in_sizes, int n_in,
                              void* d_out, int out_size, void* d_ws, size_t ws_size,
                              hipStream_t stream) {
    const float* outputs = (const float*)d_in[0];   // [16, 4096, 4]
    const float* targets = (const float*)d_in[1];   // [16, 128, 4]
    float* out = (float*)d_out;                     // C | row_ind | col_ind (as f32)

    u64* rowkey2 = (u64*)d_ws;                      // NB*NSLOT*NTGT*8 = 1 MB

    hipLaunchKernelGGL(cost_kernel, dim3(NB * NSLOT), dim3(256), 0, stream,
                       outputs, targets, out, rowkey2);
    hipLaunchKernelGGL(lsa_kernel, dim3(NB), dim3(AT), 0, stream,
                       outputs, targets, rowkey2,
                       out + CELEMS, out + CELEMS + NB * NTGT);
}